// Round 24
// baseline (105.521 us; speedup 1.0000x reference)
//
#include <hip/hip_runtime.h>

// ---------------- problem constants ----------------
#define NB    1024
#define NN    19
#define NF    8
#define CCH   152         // NN*NF
#define TLEN  512
#define TP    128
#define GO    16
#define KFLAT 38912       // flat K (n*2048 + t*16 + o) — g2 AND w1 natural order
#define HID   128
#define NCLS  2
#define NROWS (NB*TP)     // 131072 (b,t) rows

// FC1 GEMM split-K: 38912 = 32 * 1216 -> grid (16,32) = 512 blocks = 2.0/CU
#define KTILE 1216
#define NKT   (KFLAT / KTILE)   // 32

// merged conv+w1 grid (256-thread blocks)
#define CONVBLKS ((NB * NN) / 2)      // 9728 (2 (b,n) pairs each)
#define W1N4     ((HID * KFLAT) / 4)  // 1,245,184 float4s
#define W1BLKS   1024

typedef float  f32x4  __attribute__((ext_vector_type(4)));
typedef __bf16 bf16x8 __attribute__((ext_vector_type(8)));
typedef __bf16 bf16x4 __attribute__((ext_vector_type(4)));
typedef unsigned short u16x8 __attribute__((ext_vector_type(8)));

// async global->LDS, 16B per lane, dest = wave-uniform base + lane*16
__device__ __forceinline__ void gload16(const __bf16* g, __bf16* l) {
    __builtin_amdgcn_global_load_lds(
        (const __attribute__((address_space(1))) void*)g,
        (__attribute__((address_space(3))) void*)l, 16, 0, 0);
}

// ---------------------------------------------------------------------------
// A: merged conv_pool + w1->bf16. 256-thread blocks: threads [0,128) handle
//    (b,n) pair 2*bid, threads [128,256) pair 2*bid+1 (wave-uniform n).
//    H has only 19 planes now (zero-plane eliminated; mix uses register 0).
// ---------------------------------------------------------------------------
__global__ __launch_bounds__(256) void conv_w1(
    const float* __restrict__ x,       // [NB][NN][TLEN]
    const float* __restrict__ conv_w,  // [CCH][5]
    const float* __restrict__ conv_b,
    const float* __restrict__ bn_gamma, const float* __restrict__ bn_beta,
    const float* __restrict__ bn_mean,  const float* __restrict__ bn_var,
    __bf16* __restrict__ H,            // [NN][NROWS][8]
    const float* __restrict__ w1, __bf16* __restrict__ w1b)
{
    const int bid = blockIdx.x;
    if (bid >= CONVBLKS) {             // ---- w1 conversion lane ----
        for (int i = (bid - CONVBLKS) * 256 + threadIdx.x; i < W1N4; i += W1BLKS * 256) {
            float4 v = ((const float4*)w1)[i];
            bf16x4 r;
            r[0] = (__bf16)v.x; r[1] = (__bf16)v.y; r[2] = (__bf16)v.z; r[3] = (__bf16)v.w;
            ((bf16x4*)w1b)[i] = r;
        }
        return;
    }
    // ---- conv lane: pair index (wave-uniform within each 128-thread half) ----
    const int pi = bid * 2 + (threadIdx.x >> 7);
    const int tp = threadIdx.x & 127;
    const int b = pi / NN, n = pi - b * NN;

    const float* xr = x + ((size_t)b * NN + n) * TLEN;
    const float4 f4z = {0.f, 0.f, 0.f, 0.f};
    float4 L0 = (tp > 0)   ? *(const float4*)(xr + 4 * tp - 4) : f4z;
    float4 L1 =              *(const float4*)(xr + 4 * tp);
    float4 L2 = (tp < 127) ? *(const float4*)(xr + 4 * tp + 4) : f4z;
    float xv[9] = {L0.z, L0.w, L1.x, L1.y, L1.z, L1.w, L2.x, L2.y, L2.z};

    const float* cw = conv_w + n * (NF * 5);

    union { __bf16 h[8]; u16x8 v; } hv;
    #pragma unroll
    for (int f = 0; f < NF; ++f) {
        const int c = n * NF + f;
        float inv = bn_gamma[c] * rsqrtf(bn_var[c] + 1e-5f);     // fused BN affine
        float s = inv;
        float bb = conv_b[c] * inv + bn_beta[c] - bn_mean[c] * inv;
        float w0 = cw[f*5+0], w1v = cw[f*5+1], w2 = cw[f*5+2], w3 = cw[f*5+3], w4 = cw[f*5+4];
        float m = -1e30f;
        #pragma unroll
        for (int p = 0; p < 4; ++p) {
            float a = xv[p]*w0 + xv[p+1]*w1v + xv[p+2]*w2 + xv[p+3]*w3 + xv[p+4]*w4;
            m = fmaxf(m, a * s + bb);
        }
        hv.h[f] = (__bf16)fmaxf(m, 0.f);
    }
    size_t row = (size_t)b * TP + tp;
    *(u16x8*)(H + ((size_t)n * NROWS + row) * 8) = hv.v;
}

// ---------------------------------------------------------------------------
// B: MFMA contraction (C^T form) g2 = relu(H @ m2^T + gcn_b).
//    In-block softmax + register mf synthesis (R22+). H has 19 planes;
//    the j==19 pad fragment (ks==4, jg==3) is a register zero.
// ---------------------------------------------------------------------------
__global__ __launch_bounds__(640) void mix_gcn(
    const __bf16* __restrict__ H,      // [NN][NROWS][8]
    const float* __restrict__ adj,     // [NN][NN]
    const float* __restrict__ gcn_w,   // [GO][NF]
    const float* __restrict__ gcn_b,   // [GO]
    __bf16* __restrict__ g2)           // [NB][KFLAT]
{
    __shared__ float As[NN * NN];

    const int tid  = threadIdx.x;
    const int lane = tid & 63, w = tid >> 6;   // w in [0,10)
    const int arow = lane & 15;           // = o
    const int jg   = lane >> 4;           // 0..3
    const int ct0  = w * 2;               // wave's 2 ct-tiles (n = ct0, ct0+1)

    if (tid < NN) {                        // softmax(adj) rows -> LDS
        float v[NN];
        float m = -1e30f;
        #pragma unroll
        for (int j = 0; j < NN; ++j) { v[j] = adj[tid * NN + j]; m = fmaxf(m, v[j]); }
        float s = 0.f;
        #pragma unroll
        for (int j = 0; j < NN; ++j) { v[j] = expf(v[j] - m); s += v[j]; }
        float rc = 1.f / s;
        #pragma unroll
        for (int j = 0; j < NN; ++j) As[tid * NN + j] = v[j] * rc;
    }

    const float4 gbv = *(const float4*)(gcn_b + jg * 4);
    float gw[8];
    #pragma unroll
    for (int e = 0; e < 8; ++e) gw[e] = gcn_w[arow * NF + e];

    __syncthreads();

    bf16x8 mf[2][5];
    #pragma unroll
    for (int ct = 0; ct < 2; ++ct) {
        const int n = ct0 + ct;
        #pragma unroll
        for (int ks = 0; ks < 5; ++ks) {
            const int j = ks * 4 + jg;
            const float a = (n < NN && j < NN) ? As[n * NN + j] : 0.f;
            #pragma unroll
            for (int e = 0; e < 8; ++e) mf[ct][ks][e] = (__bf16)(a * gw[e]);
        }
    }

    const int b = blockIdx.x;             // one block = one batch (128 rows)
    const __bf16* hbase = H + (size_t)arow * 8 + (size_t)jg * (NROWS * 8);
    const bf16x8 zf = {};                 // register zero for j==19 pad

    bf16x8 afb[2][5];
    #pragma unroll
    for (int ks = 0; ks < 4; ++ks)
        afb[0][ks] = *(const bf16x8*)(hbase + ((size_t)b * TP) * 8 + (size_t)ks * 4 * (NROWS * 8));
    afb[0][4] = (jg == 3) ? zf
              : *(const bf16x8*)(hbase + ((size_t)b * TP) * 8 + (size_t)16 * (NROWS * 8));

    #pragma unroll
    for (int it = 0; it < 8; ++it) {
        if (it + 1 < 8) {
            const size_t ro = ((size_t)b * TP + (it + 1) * 16) * 8;
            #pragma unroll
            for (int ks = 0; ks < 4; ++ks)
                afb[(it + 1) & 1][ks] = *(const bf16x8*)(hbase + ro + (size_t)ks * 4 * (NROWS * 8));
            afb[(it + 1) & 1][4] = (jg == 3) ? zf
                                 : *(const bf16x8*)(hbase + ro + (size_t)16 * (NROWS * 8));
        }

        f32x4 acc[2];
        #pragma unroll
        for (int ct = 0; ct < 2; ++ct) acc[ct] = (f32x4){0.f, 0.f, 0.f, 0.f};

        #pragma unroll
        for (int ks = 0; ks < 5; ++ks)
            #pragma unroll
            for (int ct = 0; ct < 2; ++ct)
                acc[ct] = __builtin_amdgcn_mfma_f32_16x16x32_bf16(mf[ct][ks], afb[it & 1][ks], acc[ct], 0, 0, 0);

        const int t = it * 16 + arow;
        __bf16* gb2 = g2 + (size_t)b * KFLAT + t * 16 + jg * 4;
        #pragma unroll
        for (int ct = 0; ct < 2; ++ct) {
            const int n = ct0 + ct;
            if (n < NN) {                 // guard pad tile (wave 9, ct 1)
                bf16x4 v;
                v[0] = (__bf16)fmaxf(acc[ct][0] + gbv.x, 0.f);
                v[1] = (__bf16)fmaxf(acc[ct][1] + gbv.y, 0.f);
                v[2] = (__bf16)fmaxf(acc[ct][2] + gbv.z, 0.f);
                v[3] = (__bf16)fmaxf(acc[ct][3] + gbv.w, 0.f);
                *(bf16x4*)(gb2 + n * (TP * GO)) = v;
            }
        }
    }
}

// ---------------------------------------------------------------------------
// G: split-K bf16 MFMA GEMM (R23 proven: KTILE=1216, 512 blocks = 2/CU,
//    gload_lds staging with chunk-XOR swizzle, bf16 partial)
// ---------------------------------------------------------------------------
__global__ __launch_bounds__(256) void gemm_fc1(
    const __bf16* __restrict__ gmat,   // [NB][KFLAT]
    const __bf16* __restrict__ wmat,   // [HID][KFLAT]
    __bf16* __restrict__ partial)      // [NKT][NB][HID] bf16
{
    __shared__ __align__(16) __bf16 At[64][32];
    __shared__ __align__(16) __bf16 Bt[128][32];

    const int tid = threadIdx.x;
    const int b0 = blockIdx.x * 64;       // 16 m-tiles of 64 rows
    const int k0 = blockIdx.y * KTILE;

    const int lane = tid & 63;
    const int w = tid >> 6;
    const int wm = (w >> 1) * 32;         // 0 / 32
    const int wn = (w & 1) * 64;          // 0 / 64

    const int srow_off = lane >> 2;                      // 0..15
    const int schunk   = ((lane & 3) ^ (srow_off & 3)) * 8;

    f32x4 acc[2][4];
    #pragma unroll
    for (int m = 0; m < 2; ++m)
        #pragma unroll
        for (int n = 0; n < 4; ++n) acc[m][n] = (f32x4){0.f, 0.f, 0.f, 0.f};

    const int arow = lane & 15;
    const int rsw  = ((lane >> 4) ^ (arow & 3)) * 8;

    for (int ks = 0; ks < KTILE / 32; ++ks) {            // 38 iters
        const int gk = k0 + ks * 32;
        const int ra = w * 16;            // A rows (64 total, 1 call/wave)
        const int rb0 = w * 16;           // B rows call 0
        const int rb1 = 64 + w * 16;      // B rows call 1
        gload16(gmat + (size_t)(b0 + ra + srow_off) * KFLAT + gk + schunk, &At[ra][0]);
        gload16(wmat + (size_t)(rb0 + srow_off) * KFLAT + gk + schunk, &Bt[rb0][0]);
        gload16(wmat + (size_t)(rb1 + srow_off) * KFLAT + gk + schunk, &Bt[rb1][0]);
        __syncthreads();

        bf16x8 af[2], bfr[4];
        #pragma unroll
        for (int m = 0; m < 2; ++m) af[m]  = *(const bf16x8*)(&At[0][0] + (wm + m * 16 + arow) * 32 + rsw);
        #pragma unroll
        for (int n = 0; n < 4; ++n) bfr[n] = *(const bf16x8*)(&Bt[0][0] + (wn + n * 16 + arow) * 32 + rsw);
        #pragma unroll
        for (int m = 0; m < 2; ++m)
            #pragma unroll
            for (int n = 0; n < 4; ++n)
                acc[m][n] = __builtin_amdgcn_mfma_f32_16x16x32_bf16(af[m], bfr[n], acc[m][n], 0, 0, 0);
        __syncthreads();
    }

    __bf16* pout = partial + (size_t)blockIdx.y * (NB * HID);
    #pragma unroll
    for (int m = 0; m < 2; ++m) {
        const int rbase = b0 + wm + m * 16 + (lane >> 4) * 4;
        #pragma unroll
        for (int n = 0; n < 4; ++n) {
            const int col = wn + n * 16 + (lane & 15);
            #pragma unroll
            for (int r = 0; r < 4; ++r)
                pout[(size_t)(rbase + r) * HID + col] = (__bf16)acc[m][n][r];
        }
    }
}

// ---------------------------------------------------------------------------
// R: reduce split-K bf16 partials + b1 + ReLU, then FC2 (128->2) + b2
// ---------------------------------------------------------------------------
__global__ __launch_bounds__(128) void reduce_fc2(
    const __bf16* __restrict__ partial, // [NKT][NB][HID] bf16
    const float* __restrict__ b1,
    const float* __restrict__ w2,       // [NCLS][HID]
    const float* __restrict__ b2,
    float* __restrict__ out)            // [NB][NCLS]
{
    __shared__ float red0[128], red1[128];
    const int b = blockIdx.x, j = threadIdx.x;
    float s = b1[j];
    #pragma unroll 4
    for (int p = 0; p < NKT; ++p)
        s += (float)partial[(size_t)p * (NB * HID) + b * HID + j];
    float h = fmaxf(s, 0.f);
    red0[j] = h * w2[j];
    red1[j] = h * w2[HID + j];
    __syncthreads();
    for (int off = 64; off > 0; off >>= 1) {
        if (j < off) { red0[j] += red0[j + off]; red1[j] += red1[j + off]; }
        __syncthreads();
    }
    if (j == 0) {
        out[b * 2 + 0] = red0[0] + b2[0];
        out[b * 2 + 1] = red1[0] + b2[1];
    }
}

// ---------------------------------------------------------------------------
extern "C" void kernel_launch(void* const* d_in, const int* in_sizes, int n_in,
                              void* d_out, int out_size, void* d_ws, size_t ws_size,
                              hipStream_t stream) {
    const float* x        = (const float*)d_in[0];
    const float* conv_w   = (const float*)d_in[1];
    const float* conv_b   = (const float*)d_in[2];
    const float* bn_gamma = (const float*)d_in[3];
    const float* bn_beta  = (const float*)d_in[4];
    const float* bn_mean  = (const float*)d_in[5];
    const float* bn_var   = (const float*)d_in[6];
    const float* adj      = (const float*)d_in[7];
    const float* gcn_w    = (const float*)d_in[8];
    const float* gcn_b    = (const float*)d_in[9];
    const float* w1       = (const float*)d_in[10];
    const float* b1       = (const float*)d_in[11];
    const float* w2       = (const float*)d_in[12];
    const float* b2       = (const float*)d_in[13];
    float* out = (float*)d_out;

    // workspace (ws_size = 256 MiB; no aliasing):
    //   g2   [0,            79,691,776)
    //   H    [79,691,776,  119,537,664)   19 planes x 131072 x 16B
    //   w1b  [121,634,816, 131,596,288)
    //   part [131,596,288, 139,984,896)   32 x 1024 x 128 bf16
    char* ws = (char*)d_ws;
    __bf16* g2   = (__bf16*)ws;
    __bf16* Hbuf = (__bf16*)(ws + 79691776);
    __bf16* w1b  = (__bf16*)(ws + 121634816);
    __bf16* part = (__bf16*)(ws + 131596288);

    conv_w1<<<dim3(CONVBLKS + W1BLKS), dim3(256), 0, stream>>>(
        x, conv_w, conv_b, bn_gamma, bn_beta, bn_mean, bn_var, Hbuf, w1, w1b);
    mix_gcn<<<dim3(NB), dim3(640), 0, stream>>>(Hbuf, adj, gcn_w, gcn_b, g2);
    gemm_fc1<<<dim3(16, NKT), dim3(256), 0, stream>>>(g2, w1b, part);
    reduce_fc2<<<dim3(NB), dim3(128), 0, stream>>>(part, b1, w2, b2, out);
}

// Round 25
// 94.725 us; speedup vs baseline: 1.1140x; 1.1140x over previous
//
#include <hip/hip_runtime.h>

// ---------------- problem constants ----------------
#define NB    1024
#define NN    19
#define NF    8
#define CCH   152         // NN*NF
#define TLEN  512
#define TP    128
#define GO    16
#define KFLAT 38912       // flat K (n*2048 + t*16 + o) — g2 AND w1 natural order
#define HID   128
#define NCLS  2
#define NROWS (NB*TP)     // 131072 (b,t) rows
#define NJP   20          // H j-planes (19 + zero pad)

// FC1 GEMM split-K: 38912 = 32 * 1216 -> grid (16,32) = 512 blocks = 2.0/CU
#define KTILE 1216
#define NKT   (KFLAT / KTILE)   // 32

// merged conv+w1 grid
#define W1N4    ((HID * KFLAT) / 4)   // 1,245,184 float4s
#define W1BLKS  2048

typedef float  f32x4  __attribute__((ext_vector_type(4)));
typedef __bf16 bf16x8 __attribute__((ext_vector_type(8)));
typedef __bf16 bf16x4 __attribute__((ext_vector_type(4)));
typedef unsigned short u16x8 __attribute__((ext_vector_type(8)));

// async global->LDS, 16B per lane, dest = wave-uniform base + lane*16
__device__ __forceinline__ void gload16(const __bf16* g, __bf16* l) {
    __builtin_amdgcn_global_load_lds(
        (const __attribute__((address_space(1))) void*)g,
        (__attribute__((address_space(3))) void*)l, 16, 0, 0);
}

// ---------------------------------------------------------------------------
// A: merged conv_pool + w1->bf16 (R23 champion: 128-thread blocks,
//    wave-uniform n, in-block BN affine)
// ---------------------------------------------------------------------------
__global__ __launch_bounds__(128) void conv_w1(
    const float* __restrict__ x,       // [NB][NN][TLEN]
    const float* __restrict__ conv_w,  // [CCH][5]
    const float* __restrict__ conv_b,
    const float* __restrict__ bn_gamma, const float* __restrict__ bn_beta,
    const float* __restrict__ bn_mean,  const float* __restrict__ bn_var,
    __bf16* __restrict__ H,            // [NJP][NROWS][8]
    const float* __restrict__ w1, __bf16* __restrict__ w1b)
{
    const int bid = blockIdx.x;
    if (bid >= NB * NN) {              // ---- w1 conversion lane ----
        for (int i = (bid - NB * NN) * 128 + threadIdx.x; i < W1N4; i += W1BLKS * 128) {
            float4 v = ((const float4*)w1)[i];
            bf16x4 r;
            r[0] = (__bf16)v.x; r[1] = (__bf16)v.y; r[2] = (__bf16)v.z; r[3] = (__bf16)v.w;
            ((bf16x4*)w1b)[i] = r;
        }
        return;
    }
    // ---- conv lane ----
    const int b = bid / NN, n = bid - b * NN;
    const int tp = threadIdx.x;

    const float* xr = x + ((size_t)b * NN + n) * TLEN;
    const float4 f4z = {0.f, 0.f, 0.f, 0.f};
    float4 L0 = (tp > 0)   ? *(const float4*)(xr + 4 * tp - 4) : f4z;
    float4 L1 =              *(const float4*)(xr + 4 * tp);
    float4 L2 = (tp < 127) ? *(const float4*)(xr + 4 * tp + 4) : f4z;
    float xv[9] = {L0.z, L0.w, L1.x, L1.y, L1.z, L1.w, L2.x, L2.y, L2.z};

    const float* cw = conv_w + n * (NF * 5);

    union { __bf16 h[8]; u16x8 v; } hv;
    #pragma unroll
    for (int f = 0; f < NF; ++f) {
        const int c = n * NF + f;
        float inv = bn_gamma[c] * rsqrtf(bn_var[c] + 1e-5f);     // fused BN affine
        float s = inv;
        float bb = conv_b[c] * inv + bn_beta[c] - bn_mean[c] * inv;
        float w0 = cw[f*5+0], w1v = cw[f*5+1], w2 = cw[f*5+2], w3 = cw[f*5+3], w4 = cw[f*5+4];
        float m = -1e30f;
        #pragma unroll
        for (int p = 0; p < 4; ++p) {
            float a = xv[p]*w0 + xv[p+1]*w1v + xv[p+2]*w2 + xv[p+3]*w3 + xv[p+4]*w4;
            m = fmaxf(m, a * s + bb);
        }
        hv.h[f] = (__bf16)fmaxf(m, 0.f);
    }
    size_t row = (size_t)b * TP + tp;
    *(u16x8*)(H + ((size_t)n * NROWS + row) * 8) = hv.v;
    if (n == NN - 1) {                         // zero plane j=19 (K pad)
        u16x8 z = {0,0,0,0,0,0,0,0};
        *(u16x8*)(H + ((size_t)(NJP - 1) * NROWS + row) * 8) = z;
    }
}

// ---------------------------------------------------------------------------
// B: MFMA contraction (C^T form) g2 = relu(H @ m2^T + gcn_b)
//    (R23 champion: in-block softmax + register mf synthesis)
// ---------------------------------------------------------------------------
__global__ __launch_bounds__(640) void mix_gcn(
    const __bf16* __restrict__ H,      // [NJP][NROWS][8]
    const float* __restrict__ adj,     // [NN][NN]
    const float* __restrict__ gcn_w,   // [GO][NF]
    const float* __restrict__ gcn_b,   // [GO]
    __bf16* __restrict__ g2)           // [NB][KFLAT]
{
    __shared__ float As[NN * NN];

    const int tid  = threadIdx.x;
    const int lane = tid & 63, w = tid >> 6;   // w in [0,10)
    const int arow = lane & 15;           // = o
    const int jg   = lane >> 4;           // 0..3
    const int ct0  = w * 2;               // wave's 2 ct-tiles (n = ct0, ct0+1)

    if (tid < NN) {                        // softmax(adj) rows -> LDS
        float v[NN];
        float m = -1e30f;
        #pragma unroll
        for (int j = 0; j < NN; ++j) { v[j] = adj[tid * NN + j]; m = fmaxf(m, v[j]); }
        float s = 0.f;
        #pragma unroll
        for (int j = 0; j < NN; ++j) { v[j] = expf(v[j] - m); s += v[j]; }
        float rc = 1.f / s;
        #pragma unroll
        for (int j = 0; j < NN; ++j) As[tid * NN + j] = v[j] * rc;
    }

    const float4 gbv = *(const float4*)(gcn_b + jg * 4);
    float gw[8];
    #pragma unroll
    for (int e = 0; e < 8; ++e) gw[e] = gcn_w[arow * NF + e];

    __syncthreads();

    bf16x8 mf[2][5];
    #pragma unroll
    for (int ct = 0; ct < 2; ++ct) {
        const int n = ct0 + ct;
        #pragma unroll
        for (int ks = 0; ks < 5; ++ks) {
            const int j = ks * 4 + jg;
            const float a = (n < NN && j < NN) ? As[n * NN + j] : 0.f;
            #pragma unroll
            for (int e = 0; e < 8; ++e) mf[ct][ks][e] = (__bf16)(a * gw[e]);
        }
    }

    const int b = blockIdx.x;             // one block = one batch (128 rows)
    const __bf16* hbase = H + (size_t)arow * 8 + (size_t)jg * (NROWS * 8);

    bf16x8 afb[2][5];
    #pragma unroll
    for (int ks = 0; ks < 5; ++ks)
        afb[0][ks] = *(const bf16x8*)(hbase + ((size_t)b * TP) * 8 + (size_t)ks * 4 * (NROWS * 8));

    #pragma unroll
    for (int it = 0; it < 8; ++it) {
        if (it + 1 < 8) {
            #pragma unroll
            for (int ks = 0; ks < 5; ++ks)
                afb[(it + 1) & 1][ks] = *(const bf16x8*)(
                    hbase + ((size_t)b * TP + (it + 1) * 16) * 8 + (size_t)ks * 4 * (NROWS * 8));
        }

        f32x4 acc[2];
        #pragma unroll
        for (int ct = 0; ct < 2; ++ct) acc[ct] = (f32x4){0.f, 0.f, 0.f, 0.f};

        #pragma unroll
        for (int ks = 0; ks < 5; ++ks)
            #pragma unroll
            for (int ct = 0; ct < 2; ++ct)
                acc[ct] = __builtin_amdgcn_mfma_f32_16x16x32_bf16(mf[ct][ks], afb[it & 1][ks], acc[ct], 0, 0, 0);

        const int t = it * 16 + arow;
        __bf16* gb2 = g2 + (size_t)b * KFLAT + t * 16 + jg * 4;
        #pragma unroll
        for (int ct = 0; ct < 2; ++ct) {
            const int n = ct0 + ct;
            if (n < NN) {                 // guard pad tile (wave 9, ct 1)
                bf16x4 v;
                v[0] = (__bf16)fmaxf(acc[ct][0] + gbv.x, 0.f);
                v[1] = (__bf16)fmaxf(acc[ct][1] + gbv.y, 0.f);
                v[2] = (__bf16)fmaxf(acc[ct][2] + gbv.z, 0.f);
                v[3] = (__bf16)fmaxf(acc[ct][3] + gbv.w, 0.f);
                *(bf16x4*)(gb2 + n * (TP * GO)) = v;
            }
        }
    }
}

// ---------------------------------------------------------------------------
// G: split-K bf16 MFMA GEMM (R23 champion: KTILE=1216, 512 blocks = 2/CU,
//    gload_lds staging with chunk-XOR swizzle, bf16 partial)
// ---------------------------------------------------------------------------
__global__ __launch_bounds__(256) void gemm_fc1(
    const __bf16* __restrict__ gmat,   // [NB][KFLAT]
    const __bf16* __restrict__ wmat,   // [HID][KFLAT]
    __bf16* __restrict__ partial)      // [NKT][NB][HID] bf16
{
    __shared__ __align__(16) __bf16 At[64][32];
    __shared__ __align__(16) __bf16 Bt[128][32];

    const int tid = threadIdx.x;
    const int b0 = blockIdx.x * 64;       // 16 m-tiles of 64 rows
    const int k0 = blockIdx.y * KTILE;

    const int lane = tid & 63;
    const int w = tid >> 6;
    const int wm = (w >> 1) * 32;         // 0 / 32
    const int wn = (w & 1) * 64;          // 0 / 64

    const int srow_off = lane >> 2;                      // 0..15
    const int schunk   = ((lane & 3) ^ (srow_off & 3)) * 8;

    f32x4 acc[2][4];
    #pragma unroll
    for (int m = 0; m < 2; ++m)
        #pragma unroll
        for (int n = 0; n < 4; ++n) acc[m][n] = (f32x4){0.f, 0.f, 0.f, 0.f};

    const int arow = lane & 15;
    const int rsw  = ((lane >> 4) ^ (arow & 3)) * 8;

    for (int ks = 0; ks < KTILE / 32; ++ks) {            // 38 iters
        const int gk = k0 + ks * 32;
        const int ra = w * 16;            // A rows (64 total, 1 call/wave)
        const int rb0 = w * 16;           // B rows call 0
        const int rb1 = 64 + w * 16;      // B rows call 1
        gload16(gmat + (size_t)(b0 + ra + srow_off) * KFLAT + gk + schunk, &At[ra][0]);
        gload16(wmat + (size_t)(rb0 + srow_off) * KFLAT + gk + schunk, &Bt[rb0][0]);
        gload16(wmat + (size_t)(rb1 + srow_off) * KFLAT + gk + schunk, &Bt[rb1][0]);
        __syncthreads();

        bf16x8 af[2], bfr[4];
        #pragma unroll
        for (int m = 0; m < 2; ++m) af[m]  = *(const bf16x8*)(&At[0][0] + (wm + m * 16 + arow) * 32 + rsw);
        #pragma unroll
        for (int n = 0; n < 4; ++n) bfr[n] = *(const bf16x8*)(&Bt[0][0] + (wn + n * 16 + arow) * 32 + rsw);
        #pragma unroll
        for (int m = 0; m < 2; ++m)
            #pragma unroll
            for (int n = 0; n < 4; ++n)
                acc[m][n] = __builtin_amdgcn_mfma_f32_16x16x32_bf16(af[m], bfr[n], acc[m][n], 0, 0, 0);
        __syncthreads();
    }

    __bf16* pout = partial + (size_t)blockIdx.y * (NB * HID);
    #pragma unroll
    for (int m = 0; m < 2; ++m) {
        const int rbase = b0 + wm + m * 16 + (lane >> 4) * 4;
        #pragma unroll
        for (int n = 0; n < 4; ++n) {
            const int col = wn + n * 16 + (lane & 15);
            #pragma unroll
            for (int r = 0; r < 4; ++r)
                pout[(size_t)(rbase + r) * HID + col] = (__bf16)acc[m][n][r];
        }
    }
}

// ---------------------------------------------------------------------------
// R: reduce split-K bf16 partials + b1 + ReLU, then FC2 (128->2) + b2
// ---------------------------------------------------------------------------
__global__ __launch_bounds__(128) void reduce_fc2(
    const __bf16* __restrict__ partial, // [NKT][NB][HID] bf16
    const float* __restrict__ b1,
    const float* __restrict__ w2,       // [NCLS][HID]
    const float* __restrict__ b2,
    float* __restrict__ out)            // [NB][NCLS]
{
    __shared__ float red0[128], red1[128];
    const int b = blockIdx.x, j = threadIdx.x;
    float s = b1[j];
    #pragma unroll 4
    for (int p = 0; p < NKT; ++p)
        s += (float)partial[(size_t)p * (NB * HID) + b * HID + j];
    float h = fmaxf(s, 0.f);
    red0[j] = h * w2[j];
    red1[j] = h * w2[HID + j];
    __syncthreads();
    for (int off = 64; off > 0; off >>= 1) {
        if (j < off) { red0[j] += red0[j + off]; red1[j] += red1[j + off]; }
        __syncthreads();
    }
    if (j == 0) {
        out[b * 2 + 0] = red0[0] + b2[0];
        out[b * 2 + 1] = red1[0] + b2[1];
    }
}

// ---------------------------------------------------------------------------
extern "C" void kernel_launch(void* const* d_in, const int* in_sizes, int n_in,
                              void* d_out, int out_size, void* d_ws, size_t ws_size,
                              hipStream_t stream) {
    const float* x        = (const float*)d_in[0];
    const float* conv_w   = (const float*)d_in[1];
    const float* conv_b   = (const float*)d_in[2];
    const float* bn_gamma = (const float*)d_in[3];
    const float* bn_beta  = (const float*)d_in[4];
    const float* bn_mean  = (const float*)d_in[5];
    const float* bn_var   = (const float*)d_in[6];
    const float* adj      = (const float*)d_in[7];
    const float* gcn_w    = (const float*)d_in[8];
    const float* gcn_b    = (const float*)d_in[9];
    const float* w1       = (const float*)d_in[10];
    const float* b1       = (const float*)d_in[11];
    const float* w2       = (const float*)d_in[12];
    const float* b2       = (const float*)d_in[13];
    float* out = (float*)d_out;

    // workspace (ws_size = 256 MiB; no aliasing):
    //   g2   [0,            79,691,776)
    //   H    [79,691,776,  121,634,816)   20 planes x 131072 x 16B
    //   w1b  [121,634,816, 131,596,288)
    //   part [131,596,288, 139,984,896)   32 x 1024 x 128 bf16
    char* ws = (char*)d_ws;
    __bf16* g2   = (__bf16*)ws;
    __bf16* Hbuf = (__bf16*)(ws + 79691776);
    __bf16* w1b  = (__bf16*)(ws + 121634816);
    __bf16* part = (__bf16*)(ws + 131596288);

    conv_w1<<<dim3(NB * NN + W1BLKS), dim3(128), 0, stream>>>(
        x, conv_w, conv_b, bn_gamma, bn_beta, bn_mean, bn_var, Hbuf, w1, w1b);
    mix_gcn<<<dim3(NB), dim3(640), 0, stream>>>(Hbuf, adj, gcn_w, gcn_b, g2);
    gemm_fc1<<<dim3(16, NKT), dim3(256), 0, stream>>>(g2, w1b, part);
    reduce_fc2<<<dim3(NB), dim3(128), 0, stream>>>(part, b1, w2, b2, out);
}